// Round 3
// baseline (445.079 us; speedup 1.0000x reference)
//
#include <hip/hip_runtime.h>
#include <hip/hip_bf16.h>
#include <math.h>

#define B_ 64
#define T_ 2048
#define D_ 512
#define A_ 128

typedef __bf16 bf16x8 __attribute__((ext_vector_type(8)));
typedef float  f32x4  __attribute__((ext_vector_type(4)));

// ---------------- Kernel 0: W1 [512][128] fp32 -> W1T [128][512] bf16 ----------------
__global__ __launch_bounds__(256) void prep_kernel(
    const float* __restrict__ W1, __hip_bfloat16* __restrict__ W1T)
{
    int idx = blockIdx.x * 256 + threadIdx.x;   // 64K elements, grid 256
    int k = idx >> 7;          // 0..511
    int n = idx & 127;         // 0..127
    W1T[n * D_ + k] = __float2bfloat16(W1[idx]);
}

// ---------------- Kernel 1: scores via bf16 MFMA, W1T staged in LDS ----------------
// D[n][token] = sum_k W1T[n][k] * x[token][k].
// Block: 256 thr = 4 waves, 256 tokens/block (64 tokens/wave).
// K-chunks of 128: LDS tile w1s[128 n][128+8 k] bf16 = 34 KB.
#define KC 128
#define KPAD 136

__device__ inline bf16x8 cvt8(float4 a, float4 b) {
    bf16x8 r;
    r[0] = (__bf16)a.x; r[1] = (__bf16)a.y; r[2] = (__bf16)a.z; r[3] = (__bf16)a.w;
    r[4] = (__bf16)b.x; r[5] = (__bf16)b.y; r[6] = (__bf16)b.z; r[7] = (__bf16)b.w;
    return r;
}

__device__ inline float fast_tanh(float v) {
    v = fminf(fmaxf(v, -15.f), 15.f);
    float e = __expf(2.f * v);
    return (e - 1.f) / (e + 1.f);
}

__global__ __launch_bounds__(256, 2) void scores_kernel(
    const float* __restrict__ x, const __hip_bfloat16* __restrict__ W1T_,
    const float* __restrict__ b1, const float* __restrict__ W2,
    const float* __restrict__ b2, float* __restrict__ scores)
{
    __shared__ __bf16 w1s[A_][KPAD];

    const __bf16* W1T = (const __bf16*)W1T_;
    const int tid  = threadIdx.x;
    const int wave = tid >> 6;
    const int lane = tid & 63;
    const int col  = lane & 15;    // token within 16-tile / A row select
    const int kgrp = lane >> 4;    // 0..3

    const long tokbase = (long)blockIdx.x * 256 + wave * 64;

    f32x4 acc[8][4];
#pragma unroll
    for (int mt = 0; mt < 8; mt++)
#pragma unroll
        for (int tt = 0; tt < 4; tt++)
            acc[mt][tt] = (f32x4){0.f, 0.f, 0.f, 0.f};

    const float* xp = x + (tokbase + col) * D_;

    for (int kc = 0; kc < D_; kc += KC) {
        // stage W1T K-chunk into LDS: 128 rows x 128 k
        __syncthreads();
        {
            int n = tid >> 4;            // 0..15? -> need 128 rows over 8 iters
#pragma unroll
            for (int i = 0; i < 8; i++) {
                int idx = tid + i * 256;          // 0..2047
                int row = idx >> 4;               // 0..127
                int kslot = idx & 15;             // 16 B units
                *(bf16x8*)&w1s[row][kslot * 8] =
                    *(const bf16x8*)(W1T + (long)row * D_ + kc + kslot * 8);
            }
            (void)n;
        }
        __syncthreads();

#pragma unroll
        for (int ks = 0; ks < 4; ks++) {
            const int klane = kc + ks * 32 + kgrp * 8;
            bf16x8 bf[4];
#pragma unroll
            for (int tt = 0; tt < 4; tt++) {
                float4 a = *(const float4*)(xp + (long)tt * 16 * D_ + klane);
                float4 b = *(const float4*)(xp + (long)tt * 16 * D_ + klane + 4);
                bf[tt] = cvt8(a, b);
            }
#pragma unroll
            for (int mt = 0; mt < 8; mt++) {
                bf16x8 af = *(const bf16x8*)&w1s[mt * 16 + col][ks * 32 + kgrp * 8];
#pragma unroll
                for (int tt = 0; tt < 4; tt++)
                    acc[mt][tt] = __builtin_amdgcn_mfma_f32_16x16x32_bf16(af, bf[tt], acc[mt][tt], 0, 0, 0);
            }
        }
    }

    // epilogue: n = mt*16 + kgrp*4 + r ; token = tokbase + tt*16 + col
    float p[4] = {0.f, 0.f, 0.f, 0.f};
#pragma unroll
    for (int mt = 0; mt < 8; mt++) {
#pragma unroll
        for (int r = 0; r < 4; r++) {
            int n = mt * 16 + kgrp * 4 + r;
            float bb = b1[n];
            float ww = W2[n];
#pragma unroll
            for (int tt = 0; tt < 4; tt++)
                p[tt] += fast_tanh(acc[mt][tt][r] + bb) * ww;
        }
    }
#pragma unroll
    for (int tt = 0; tt < 4; tt++) {
        p[tt] += __shfl_xor(p[tt], 16, 64);
        p[tt] += __shfl_xor(p[tt], 32, 64);
    }
    if (lane < 16) {
        float bias = b2[0];
#pragma unroll
        for (int tt = 0; tt < 4; tt++)
            scores[tokbase + tt * 16 + col] = p[tt] + bias;
    }
}

// ---------------- Kernel 2: softmax over T per batch ----------------
__global__ __launch_bounds__(256) void softmax_kernel(
    const float* __restrict__ scores, float* __restrict__ w)
{
    const int b = blockIdx.x;
    const int tid = threadIdx.x;
    const float* s = scores + (long)b * T_;

    float v[8];
    float mx = -1e30f;
#pragma unroll
    for (int j = 0; j < 8; j++) {
        v[j] = s[tid + j * 256];
        mx = fmaxf(mx, v[j]);
    }
#pragma unroll
    for (int off = 1; off < 64; off <<= 1)
        mx = fmaxf(mx, __shfl_xor(mx, off, 64));
    __shared__ float redm[4];
    if ((tid & 63) == 0) redm[tid >> 6] = mx;
    __syncthreads();
    mx = fmaxf(fmaxf(redm[0], redm[1]), fmaxf(redm[2], redm[3]));

    float sum = 0.f;
#pragma unroll
    for (int j = 0; j < 8; j++) {
        v[j] = __expf(v[j] - mx);
        sum += v[j];
    }
#pragma unroll
    for (int off = 1; off < 64; off <<= 1)
        sum += __shfl_xor(sum, off, 64);
    __shared__ float reds[4];
    if ((tid & 63) == 0) reds[tid >> 6] = sum;
    __syncthreads();
    sum = reds[0] + reds[1] + reds[2] + reds[3];
    const float inv = 1.0f / sum;
#pragma unroll
    for (int j = 0; j < 8; j++)
        w[(long)b * T_ + tid + j * 256] = v[j] * inv;
}

// ---------------- Kernel 3: pooling partials (contiguous rows) ----------------
// grid: 64 b x 16 chunks of 128 tokens. 256 threads: 2 full rows (512 f) per iter.
__global__ __launch_bounds__(256) void pool_partial_kernel(
    const float* __restrict__ x, const float* __restrict__ w,
    float* __restrict__ pmu, float* __restrict__ pm2)
{
    const int blk = blockIdx.x;
    const int b = blk >> 4;
    const int t0 = (blk & 15) * 128;
    const int tid = threadIdx.x;
    const int half = tid >> 7;        // 0/1: which of 2 rows per iter
    const int dq = tid & 127;         // float4 index over D=512

    const float* wb = w + (long)b * T_ + t0;
    const float* xb = x + ((long)b * T_ + t0) * D_ + dq * 4;

    float4 mu = {0.f, 0.f, 0.f, 0.f};
    float4 m2 = {0.f, 0.f, 0.f, 0.f};

#pragma unroll 4
    for (int t = half; t < 128; t += 2) {
        float wt = wb[t];
        float4 xv = *(const float4*)(xb + (long)t * D_);
        mu.x = fmaf(wt, xv.x, mu.x);
        mu.y = fmaf(wt, xv.y, mu.y);
        mu.z = fmaf(wt, xv.z, mu.z);
        mu.w = fmaf(wt, xv.w, mu.w);
        m2.x = fmaf(wt * xv.x, xv.x, m2.x);
        m2.y = fmaf(wt * xv.y, xv.y, m2.y);
        m2.z = fmaf(wt * xv.z, xv.z, m2.z);
        m2.w = fmaf(wt * xv.w, xv.w, m2.w);
    }

    __shared__ float4 smu[256];
    __shared__ float4 sm2[256];
    smu[tid] = mu;
    sm2[tid] = m2;
    __syncthreads();

    if (tid < 128) {
        float4 a = smu[tid], c = smu[tid + 128];
        float4 e = sm2[tid], f = sm2[tid + 128];
        a.x += c.x; a.y += c.y; a.z += c.z; a.w += c.w;
        e.x += f.x; e.y += f.y; e.z += f.z; e.w += f.w;
        *(float4*)(pmu + (long)blk * D_ + dq * 4) = a;
        *(float4*)(pm2 + (long)blk * D_ + dq * 4) = e;
    }
}

// ---------------- Kernel 4: final reduce over 16 chunks ----------------
__global__ __launch_bounds__(256) void pool_final_kernel(
    const float* __restrict__ pmu, const float* __restrict__ pm2,
    float* __restrict__ out)
{
    const int b = blockIdx.x;
    const int tid = threadIdx.x;
#pragma unroll
    for (int i = 0; i < 2; i++) {
        int d = tid + i * 256;
        float mu = 0.f, m2 = 0.f;
#pragma unroll
        for (int c = 0; c < 16; c++) {
            mu += pmu[((long)b * 16 + c) * D_ + d];
            m2 += pm2[((long)b * 16 + c) * D_ + d];
        }
        out[(long)b * (2 * D_) + d] = mu;
        out[(long)b * (2 * D_) + D_ + d] = sqrtf(fmaxf(m2 - mu * mu, 0.f) + 1e-6f);
    }
}

extern "C" void kernel_launch(void* const* d_in, const int* in_sizes, int n_in,
                              void* d_out, int out_size, void* d_ws, size_t ws_size,
                              hipStream_t stream) {
    const float* x  = (const float*)d_in[0];
    const float* W1 = (const float*)d_in[1];
    const float* b1 = (const float*)d_in[2];
    const float* W2 = (const float*)d_in[3];
    const float* b2 = (const float*)d_in[4];
    float* out = (float*)d_out;

    float* ws = (float*)d_ws;
    float* scores = ws;                                   // 131072 f
    float* w      = ws + (long)B_ * T_;                   // 131072 f
    float* pmu    = ws + 2L * B_ * T_;                    // 1024*512 f
    float* pm2    = pmu + 1024L * D_;                     // 1024*512 f
    __hip_bfloat16* W1T = (__hip_bfloat16*)(pm2 + 1024L * D_);  // 65536 bf16

    prep_kernel<<<256, 256, 0, stream>>>(W1, W1T);
    scores_kernel<<<(B_ * T_) / 256, 256, 0, stream>>>(x, W1T, b1, W2, b2, scores);
    softmax_kernel<<<B_, 256, 0, stream>>>(scores, w);
    pool_partial_kernel<<<B_ * 16, 256, 0, stream>>>(x, w, pmu, pm2);
    pool_final_kernel<<<B_, 256, 0, stream>>>(pmu, pm2, out);
}